// Round 1
// 659.578 us; speedup vs baseline: 1.3451x; 1.3451x over previous
//
#include <hip/hip_runtime.h>
#include <hip/hip_bf16.h>
#include <cstdint>

// GCNModelVAE forward, fp32 accumulate, dtype-dual (bf16 OR f32 I/O).
//   G1: S1T[256,8192]  = (x @ Wh)^T
//   G2: Hacc[8192,256] += adj @ S1   (split-K x8, f32 atomics) -> epi_relu -> H bf16
//   G3: TT[128,8192]   = (H @ [Wm|Wl])^T
//   G4: Zc[8192,128]   += adj @ T    (split-K x8, f32 atomics) -> epi_split
//   G5: recon          = Zm @ Zm^T   (A=B=ZmWS, NT)
//
// R4 (this round): G2/G4 were latency-bound (Occupancy 23%, MfmaUtil 4.6%,
// HBM 23%): grids of 512/256 blocks put all parallelism in a serial K=8192
// loop (~2700 cy/iter = exposed HBM latency). Split-K x8 -> 4096/2048 blocks
// (8 resident/CU), f32 atomicAdd partials + tiny epilogues. n-fastest lid
// decomposition + bijective XCD swizzle makes each XCD own one k-chunk and
// co-schedules adj-tile-sharing n-siblings on one L2.

typedef __hip_bfloat16 hbf16;
typedef __bf16 bf16x8 __attribute__((ext_vector_type(8)));
typedef __bf16 bf16x4 __attribute__((ext_vector_type(4)));
typedef float  f32x4  __attribute__((ext_vector_type(4)));

#define N_NODES 8192
#define D_INF   512
#define D_HID   256
#define D_Z     64
#define KSPLIT  8

enum { EPI_NORM = 0, EPI_RELU = 1, EPI_TRANS = 2, EPI_SPLIT = 3 };

__device__ __forceinline__ float tofloat(float v) { return v; }
__device__ __forceinline__ float tofloat(hbf16 v) { return __bfloat162float(v); }

__device__ __forceinline__ bf16x8 load8(const hbf16* p) {
    return *(const bf16x8*)p;
}
__device__ __forceinline__ bf16x8 load8(const float* p) {
    f32x4 f0 = *(const f32x4*)p;
    f32x4 f1 = *(const f32x4*)(p + 4);
    bf16x8 r;
    r[0] = (__bf16)f0[0]; r[1] = (__bf16)f0[1];
    r[2] = (__bf16)f0[2]; r[3] = (__bf16)f0[3];
    r[4] = (__bf16)f1[0]; r[5] = (__bf16)f1[1];
    r[6] = (__bf16)f1[2]; r[7] = (__bf16)f1[3];
    return r;
}

__device__ __forceinline__ void store1(float* p, float v) { *p = v; }
__device__ __forceinline__ void store1(hbf16* p, float v) { *p = __float2bfloat16(v); }

// Classify d_in[1] (adj, uniform[0,1)): bf16 data -> low u16 of each u32 word
// is a bf16 in [0,1): nonzero with top byte <= 0x3F (~100%). f32 data -> low
// u16 is random mantissa bits (~25% pass). Flag 1 = bf16.
__global__ void detect_dtype(const unsigned int* __restrict__ w, int* __restrict__ flag) {
    __shared__ int cnt;
    if (threadIdx.x == 0) cnt = 0;
    __syncthreads();
    int c = 0;
#pragma unroll
    for (int i = 0; i < 16; ++i) {
        unsigned int v = w[threadIdx.x * 16 + i];
        unsigned int lo = v & 0xFFFFu;
        if (lo != 0u && (lo >> 8) <= 0x3Fu) ++c;
    }
    atomicAdd(&cnt, c);
    __syncthreads();
    if (threadIdx.x == 0) *flag = (cnt > 2560) ? 1 : 0;   // of 4096 samples
}

// ---------------------------------------------------------------------------
// NT GEMM, 64x64 tile, BK=64, 4 waves (each 32x32 via 2x2 of 16x16x32 bf16
// MFMA). A: dtype TA; B: always bf16 (ws intermediates); out: TOUT.
// Used for G1 (TRANS), G3 (TRANS), G5 (NORM).
template <int EPI, int PIPE, typename TA, typename TOUT>
__global__ __launch_bounds__(256)
void gemm_nt64(const int* __restrict__ flag,
               const TA* __restrict__ A, int lda,
               const hbf16* __restrict__ B, int ldb,
               TOUT* __restrict__ C0, TOUT* __restrict__ C1,
               hbf16* __restrict__ CWS, int ldc, int K)
{
    if ((*flag != 0) != (PIPE != 0)) return;   // uniform: dead pipeline exits

    __shared__ hbf16 As[64 * 64];
    __shared__ hbf16 Bs[64 * 64];

    const int tid  = threadIdx.x;
    const int lane = tid & 63;
    const int w    = tid >> 6;        // wave 0..3
    const int wm0  = (w >> 1) * 32;   // wave's 32x32 quadrant
    const int wn0  = (w & 1) * 32;

    const int m0 = blockIdx.y * 64;
    const int n0 = blockIdx.x * 64;

    const int srow = tid >> 3;            // 0..31
    const int scol = (tid & 7) * 8;       // element col

    const size_t a_base = (size_t)(m0 + srow) * lda + scol;
    const size_t b_base = (size_t)(n0 + srow) * ldb + scol;

    f32x4 acc[2][2];
#pragma unroll
    for (int i = 0; i < 2; ++i)
#pragma unroll
        for (int j = 0; j < 2; ++j)
            acc[i][j] = (f32x4){0.f, 0.f, 0.f, 0.f};

    const int mrow = lane & 15;          // fragment row within 16
    const int kq   = (lane >> 4) * 8;    // quad * 8 along K

    for (int k0 = 0; k0 < K; k0 += 64) {
        bf16x8 va0 = load8(A + a_base + k0);
        bf16x8 va1 = load8(A + a_base + (size_t)32 * lda + k0);
        bf16x8 vb0 = load8(B + b_base + k0);
        bf16x8 vb1 = load8(B + b_base + (size_t)32 * ldb + k0);

        __syncthreads();   // previous iter's ds_reads done before overwrite
        *(bf16x8*)&As[srow * 64 + scol]        = va0;
        *(bf16x8*)&As[(srow + 32) * 64 + scol] = va1;
        *(bf16x8*)&Bs[srow * 64 + scol]        = vb0;
        *(bf16x8*)&Bs[(srow + 32) * 64 + scol] = vb1;
        __syncthreads();   // staged

#pragma unroll
        for (int ks = 0; ks < 2; ++ks) {
            bf16x8 a0 = *(const bf16x8*)&As[(wm0 + mrow) * 64 + ks * 32 + kq];
            bf16x8 a1 = *(const bf16x8*)&As[(wm0 + 16 + mrow) * 64 + ks * 32 + kq];
            bf16x8 b0 = *(const bf16x8*)&Bs[(wn0 + mrow) * 64 + ks * 32 + kq];
            bf16x8 b1 = *(const bf16x8*)&Bs[(wn0 + 16 + mrow) * 64 + ks * 32 + kq];
            acc[0][0] = __builtin_amdgcn_mfma_f32_16x16x32_bf16(a0, b0, acc[0][0], 0, 0, 0);
            acc[0][1] = __builtin_amdgcn_mfma_f32_16x16x32_bf16(a0, b1, acc[0][1], 0, 0, 0);
            acc[1][0] = __builtin_amdgcn_mfma_f32_16x16x32_bf16(a1, b0, acc[1][0], 0, 0, 0);
            acc[1][1] = __builtin_amdgcn_mfma_f32_16x16x32_bf16(a1, b1, acc[1][1], 0, 0, 0);
        }
    }

    // epilogue: C/D layout col=lane&15, row=(lane>>4)*4+reg  [m89/m91]
    const int cn = lane & 15;
    const int rq = (lane >> 4) * 4;
#pragma unroll
    for (int mt = 0; mt < 2; ++mt)
#pragma unroll
        for (int nt = 0; nt < 2; ++nt)
#pragma unroll
            for (int r = 0; r < 4; ++r) {
                int row = m0 + wm0 + mt * 16 + rq + r;
                int col = n0 + wn0 + nt * 16 + cn;
                float v = acc[mt][nt][r];
                if (EPI == EPI_RELU) v = v > 0.f ? v : 0.f;
                if (EPI == EPI_TRANS) {
                    store1(&C0[(size_t)col * ldc + row], v);
                } else if (EPI == EPI_SPLIT) {
                    if (col < D_Z) {
                        store1(&C0[(size_t)row * D_Z + col], v);
                        CWS[(size_t)row * D_Z + col] = __float2bfloat16(v);
                    } else {
                        store1(&C1[(size_t)row * D_Z + (col - D_Z)], v);
                    }
                } else {
                    store1(&C0[(size_t)row * ldc + col], v);
                }
            }
}

// ---------------------------------------------------------------------------
// Split-K x8 variant for the two adj GEMMs (K = 8192). 1-D grid of
// NBLK * (N_NODES/64) * KSPLIT blocks; lid decomposition n-fastest, then m,
// then k; bijective XCD swizzle so each XCD owns one k-chunk and n-siblings
// sharing an adj tile are co-resident on one L2. f32 atomicAdd epilogue
// (device-scope, G12) into a zeroed workspace buffer.
template <int PIPE, int NBLK, typename TA>
__global__ __launch_bounds__(256)
void gemm_nt64_splitk(const int* __restrict__ flag,
                      const TA* __restrict__ A, int lda,
                      const hbf16* __restrict__ B, int ldb,
                      float* __restrict__ C, int ldc, int K)
{
    if ((*flag != 0) != (PIPE != 0)) return;

    __shared__ hbf16 As[64 * 64];
    __shared__ hbf16 Bs[64 * 64];

    // grid size divisible by 8 by construction
    const int q   = gridDim.x >> 3;
    const int lid = ((int)blockIdx.x & 7) * q + ((int)blockIdx.x >> 3);
    const int nb  = lid & (NBLK - 1);
    const int rem = lid / NBLK;
    const int mb  = rem & (N_NODES / 64 - 1);
    const int kb  = rem / (N_NODES / 64);

    const int tid  = threadIdx.x;
    const int lane = tid & 63;
    const int w    = tid >> 6;
    const int wm0  = (w >> 1) * 32;
    const int wn0  = (w & 1) * 32;

    const int m0 = mb * 64;
    const int n0 = nb * 64;

    const int srow = tid >> 3;
    const int scol = (tid & 7) * 8;

    const size_t a_base = (size_t)(m0 + srow) * lda + scol;
    const size_t b_base = (size_t)(n0 + srow) * ldb + scol;

    f32x4 acc[2][2];
#pragma unroll
    for (int i = 0; i < 2; ++i)
#pragma unroll
        for (int j = 0; j < 2; ++j)
            acc[i][j] = (f32x4){0.f, 0.f, 0.f, 0.f};

    const int mrow = lane & 15;
    const int kq   = (lane >> 4) * 8;

    const int kchunk = K / KSPLIT;
    const int k_lo   = kb * kchunk;
    const int k_hi   = k_lo + kchunk;

    for (int k0 = k_lo; k0 < k_hi; k0 += 64) {
        bf16x8 va0 = load8(A + a_base + k0);
        bf16x8 va1 = load8(A + a_base + (size_t)32 * lda + k0);
        bf16x8 vb0 = load8(B + b_base + k0);
        bf16x8 vb1 = load8(B + b_base + (size_t)32 * ldb + k0);

        __syncthreads();
        *(bf16x8*)&As[srow * 64 + scol]        = va0;
        *(bf16x8*)&As[(srow + 32) * 64 + scol] = va1;
        *(bf16x8*)&Bs[srow * 64 + scol]        = vb0;
        *(bf16x8*)&Bs[(srow + 32) * 64 + scol] = vb1;
        __syncthreads();

#pragma unroll
        for (int ks = 0; ks < 2; ++ks) {
            bf16x8 a0 = *(const bf16x8*)&As[(wm0 + mrow) * 64 + ks * 32 + kq];
            bf16x8 a1 = *(const bf16x8*)&As[(wm0 + 16 + mrow) * 64 + ks * 32 + kq];
            bf16x8 b0 = *(const bf16x8*)&Bs[(wn0 + mrow) * 64 + ks * 32 + kq];
            bf16x8 b1 = *(const bf16x8*)&Bs[(wn0 + 16 + mrow) * 64 + ks * 32 + kq];
            acc[0][0] = __builtin_amdgcn_mfma_f32_16x16x32_bf16(a0, b0, acc[0][0], 0, 0, 0);
            acc[0][1] = __builtin_amdgcn_mfma_f32_16x16x32_bf16(a0, b1, acc[0][1], 0, 0, 0);
            acc[1][0] = __builtin_amdgcn_mfma_f32_16x16x32_bf16(a1, b0, acc[1][0], 0, 0, 0);
            acc[1][1] = __builtin_amdgcn_mfma_f32_16x16x32_bf16(a1, b1, acc[1][1], 0, 0, 0);
        }
    }

    const int cn = lane & 15;
    const int rq = (lane >> 4) * 4;
#pragma unroll
    for (int mt = 0; mt < 2; ++mt)
#pragma unroll
        for (int nt = 0; nt < 2; ++nt)
#pragma unroll
            for (int r = 0; r < 4; ++r) {
                int row = m0 + wm0 + mt * 16 + rq + r;
                int col = n0 + wn0 + nt * 16 + cn;
                atomicAdd(&C[(size_t)row * ldc + col], acc[mt][nt][r]);
            }
}

// ---------------------------------------------------------------------------
// zero Hacc+Zc (contiguous, 3M floats) before split-K atomics
__global__ void zero_f32(float* __restrict__ p, int n4) {
    int i = blockIdx.x * 256 + threadIdx.x;
    if (i < n4) ((f32x4*)p)[i] = (f32x4){0.f, 0.f, 0.f, 0.f};
}

// H = relu(Hacc) -> bf16, 8192*256 elements, 4/thread
template <int PIPE>
__global__ void epi_relu(const int* __restrict__ flag,
                         const float* __restrict__ S, hbf16* __restrict__ H) {
    if ((*flag != 0) != (PIPE != 0)) return;
    int i = blockIdx.x * 256 + threadIdx.x;           // 524288 total
    f32x4 v = ((const f32x4*)S)[i];
    bf16x4 o;
#pragma unroll
    for (int j = 0; j < 4; ++j) {
        float f = v[j] > 0.f ? v[j] : 0.f;
        o[j] = (__bf16)f;
    }
    ((bf16x4*)H)[i] = o;
}

// Zc[8192,128] -> zmean TOUT[8192,64] (+ bf16 ws copy), zlog TOUT[8192,64]
template <int PIPE, typename T>
__global__ void epi_split(const int* __restrict__ flag,
                          const float* __restrict__ Zc,
                          T* __restrict__ zmean, T* __restrict__ zlog,
                          hbf16* __restrict__ zws) {
    if ((*flag != 0) != (PIPE != 0)) return;
    int i = blockIdx.x * 256 + threadIdx.x;           // 262144 total
    f32x4 v = ((const f32x4*)Zc)[i];
    int i4  = i << 2;
    int row = i4 >> 7;
    int col = i4 & 127;                               // multiple of 4, one half
    if (col < D_Z) {
        size_t o = (size_t)row * D_Z + col;
#pragma unroll
        for (int j = 0; j < 4; ++j) {
            store1(&zmean[o + j], v[j]);
            zws[o + j] = __float2bfloat16(v[j]);
        }
    } else {
        size_t o = (size_t)row * D_Z + (col - D_Z);
#pragma unroll
        for (int j = 0; j < 4; ++j) store1(&zlog[o + j], v[j]);
    }
}

// Wh[512,256] -> WhT[256,512] (bf16)
template <int PIPE, typename T>
__global__ void prep_whT(const int* __restrict__ flag,
                         const T* __restrict__ W, hbf16* __restrict__ WT) {
    if ((*flag != 0) != (PIPE != 0)) return;
    int o = blockIdx.x * 256 + threadIdx.x;   // 256*512 total
    int n = o >> 9;
    int k = o & 511;
    WT[o] = __float2bfloat16(tofloat(W[k * D_HID + n]));
}

// Wm[256,64], Wl[256,64] -> WcT[128,256] (bf16; rows 0..63 = Wm^T, 64..127 = Wl^T)
template <int PIPE, typename T>
__global__ void prep_wcT(const int* __restrict__ flag,
                         const T* __restrict__ Wm, const T* __restrict__ Wl,
                         hbf16* __restrict__ WcT) {
    if ((*flag != 0) != (PIPE != 0)) return;
    int o = blockIdx.x * 256 + threadIdx.x;   // 128*256 total
    int n = o >> 8;
    int k = o & 255;
    WcT[o] = __float2bfloat16(tofloat((n < D_Z) ? Wm[k * D_Z + n]
                                                : Wl[k * D_Z + (n - D_Z)]));
}

template <int PIPE, typename T>
static void launch_pipeline(void* const* d_in, void* d_out,
                            int* flag, hbf16* S1T, hbf16* H, hbf16* WhT,
                            hbf16* WcT, hbf16* TT, hbf16* ZmWS,
                            float* Hacc, float* Zc,
                            hipStream_t stream) {
    const T* x   = (const T*)d_in[0];
    const T* adj = (const T*)d_in[1];
    const T* Wh  = (const T*)d_in[2];
    const T* Wm  = (const T*)d_in[3];
    const T* Wl  = (const T*)d_in[4];

    T* recon = (T*)d_out;                              // [8192,8192]
    T* zmean = recon + (size_t)N_NODES * N_NODES;      // [8192,64]
    T* zlog  = zmean + (size_t)N_NODES * D_Z;          // [8192,64]

    prep_whT<PIPE, T><<<512, 256, 0, stream>>>(flag, Wh, WhT);
    prep_wcT<PIPE, T><<<128, 256, 0, stream>>>(flag, Wm, Wl, WcT);

    // G1: S1T = (x @ Wh)^T        M=8192 N=256 K=512
    gemm_nt64<EPI_TRANS, PIPE, T, hbf16>
        <<<dim3(D_HID / 64, N_NODES / 64), 256, 0, stream>>>(
        flag, x, D_INF, WhT, D_INF, S1T, (hbf16*)nullptr, (hbf16*)nullptr,
        N_NODES, D_INF);

    // G2: Hacc += adj @ S1 (split-K x8)   M=8192 N=256 K=8192
    gemm_nt64_splitk<PIPE, 4, T>
        <<<4 * (N_NODES / 64) * KSPLIT, 256, 0, stream>>>(
        flag, adj, N_NODES, S1T, N_NODES, Hacc, D_HID, N_NODES);
    epi_relu<PIPE><<<2048, 256, 0, stream>>>(flag, Hacc, H);

    // G3: TT = (H @ [Wm|Wl])^T    M=8192 N=128 K=256
    gemm_nt64<EPI_TRANS, PIPE, hbf16, hbf16>
        <<<dim3(2 * D_Z / 64, N_NODES / 64), 256, 0, stream>>>(
        flag, H, D_HID, WcT, D_HID, TT, (hbf16*)nullptr, (hbf16*)nullptr,
        N_NODES, D_HID);

    // G4: Zc += adj @ T (split-K x8)      M=8192 N=128 K=8192
    gemm_nt64_splitk<PIPE, 2, T>
        <<<2 * (N_NODES / 64) * KSPLIT, 256, 0, stream>>>(
        flag, adj, N_NODES, TT, N_NODES, Zc, 2 * D_Z, N_NODES);
    epi_split<PIPE, T><<<1024, 256, 0, stream>>>(flag, Zc, zmean, zlog, ZmWS);

    // G5: recon = Zm @ Zm^T       M=8192 N=8192 K=64
    gemm_nt64<EPI_NORM, PIPE, hbf16, T>
        <<<dim3(N_NODES / 64, N_NODES / 64), 256, 0, stream>>>(
        flag, ZmWS, D_Z, ZmWS, D_Z, recon, (T*)nullptr, (hbf16*)nullptr,
        N_NODES, D_Z);
}

extern "C" void kernel_launch(void* const* d_in, const int* in_sizes, int n_in,
                              void* d_out, int out_size, void* d_ws, size_t ws_size,
                              hipStream_t stream) {
    int*   flag = (int*)d_ws;
    hbf16* S1T  = (hbf16*)((char*)d_ws + 256);                  // [256,8192]  4 MB
    hbf16* H    = S1T + (size_t)D_HID * N_NODES;                // [8192,256]  4 MB
    hbf16* WhT  = H   + (size_t)N_NODES * D_HID;                // [256,512]
    hbf16* WcT  = WhT + (size_t)D_HID * D_INF;                  // [128,256]
    hbf16* TT   = WcT + (size_t)2 * D_Z * D_HID;                // [128,8192]  2 MB
    hbf16* ZmWS = TT  + (size_t)2 * D_Z * N_NODES;              // [8192,64]   1 MB
    float* Hacc = (float*)(ZmWS + (size_t)N_NODES * D_Z);       // [8192,256]  8 MB f32
    float* Zc   = Hacc + (size_t)N_NODES * D_HID;               // [8192,128]  4 MB f32

    detect_dtype<<<1, 256, 0, stream>>>((const unsigned int*)d_in[1], flag);

    // zero split-K accumulators (Hacc|Zc contiguous: 3M floats)
    zero_f32<<<3072, 256, 0, stream>>>(
        Hacc, (N_NODES * D_HID + N_NODES * 2 * D_Z) / 4);

    launch_pipeline<1, hbf16>(d_in, d_out, flag, S1T, H, WhT, WcT, TT, ZmWS,
                              Hacc, Zc, stream);
    launch_pipeline<0, float>(d_in, d_out, flag, S1T, H, WhT, WcT, TT, ZmWS,
                              Hacc, Zc, stream);
}

// Round 3
// 611.482 us; speedup vs baseline: 1.4509x; 1.0787x over previous
//
#include <hip/hip_runtime.h>
#include <hip/hip_bf16.h>
#include <cstdint>

// GCNModelVAE forward, fp32 accumulate, dtype-dual (bf16 OR f32 I/O).
//   G1: S1T[256,8192]  = (x @ Wh)^T
//   G2: Hacc[8192,256] += adj @ S1   (split-K x8, 64x128 tiles, f32 atomics)
//   G3: TT[128,8192]   = (H @ [Wm|Wl])^T
//   G4: Zc[8192,128]   += adj @ T    (split-K x8, 64x128 full-N tiles)
//   G5: recon          = Zm @ Zm^T   (A=B=ZmWS, NT)
//
// R5: (a) T2 XOR swizzle on all LDS tiles -- [.][64] bf16 rows stride 128B,
//     every row starts at bank 0, fragment reads were ~2x serialized
//     (SQ_LDS_BANK_CONFLICT 2.5e7 measured on gemm rows).
//     (b) split-K tiles widened 64x64 -> 64x128: G4 covers full N in one
//     block (adj HBM fetch = exactly 1x by construction), G2 needs only 2
//     n-siblings sharing a tile (consecutive lids, same XCD via bijective
//     swizzle). 16 MFMA / 12 ds_read per K-step vs 8/12 before.
// R6: R5 bench died at container level (infra); source audited (bounds,
//     barrier uniformity, LDS/VGPR budget, swizzle bijectivity) -- no kernel
//     fault found; resubmitting unchanged for counters.

typedef __hip_bfloat16 hbf16;
typedef __bf16 bf16x8 __attribute__((ext_vector_type(8)));
typedef __bf16 bf16x4 __attribute__((ext_vector_type(4)));
typedef float  f32x4  __attribute__((ext_vector_type(4)));

#define N_NODES 8192
#define D_INF   512
#define D_HID   256
#define D_Z     64
#define KSPLIT  8

enum { EPI_NORM = 0, EPI_RELU = 1, EPI_TRANS = 2, EPI_SPLIT = 3 };

__device__ __forceinline__ float tofloat(float v) { return v; }
__device__ __forceinline__ float tofloat(hbf16 v) { return __bfloat162float(v); }

__device__ __forceinline__ bf16x8 load8(const hbf16* p) {
    return *(const bf16x8*)p;
}
__device__ __forceinline__ bf16x8 load8(const float* p) {
    f32x4 f0 = *(const f32x4*)p;
    f32x4 f1 = *(const f32x4*)(p + 4);
    bf16x8 r;
    r[0] = (__bf16)f0[0]; r[1] = (__bf16)f0[1];
    r[2] = (__bf16)f0[2]; r[3] = (__bf16)f0[3];
    r[4] = (__bf16)f1[0]; r[5] = (__bf16)f1[1];
    r[6] = (__bf16)f1[2]; r[7] = (__bf16)f1[3];
    return r;
}

__device__ __forceinline__ void store1(float* p, float v) { *p = v; }
__device__ __forceinline__ void store1(hbf16* p, float v) { *p = __float2bfloat16(v); }

// T2 XOR swizzle for [rows][64] bf16 LDS tiles (row stride 128 B).
// 16B-granule index XORed with row&7: fragment reads (16 rows, same col)
// spread across 8 granules -> conflict-free; bijective within each row
// since col offsets are 16B-aligned (bits 4-6).
__device__ __forceinline__ int swzoff(int row, int col) {
    int byte = (row << 7) + (col << 1);
    return byte ^ ((row & 7) << 4);
}
#define LDS8(base, row, col) (*(bf16x8*)((char*)(base) + swzoff((row), (col))))
#define LDS8C(base, row, col) (*(const bf16x8*)((const char*)(base) + swzoff((row), (col))))

// Classify d_in[1] (adj, uniform[0,1)): bf16 data -> low u16 of each u32 word
// is a bf16 in [0,1): nonzero with top byte <= 0x3F (~100%). f32 data -> low
// u16 is random mantissa bits (~25% pass). Flag 1 = bf16.
__global__ void detect_dtype(const unsigned int* __restrict__ w, int* __restrict__ flag) {
    __shared__ int cnt;
    if (threadIdx.x == 0) cnt = 0;
    __syncthreads();
    int c = 0;
#pragma unroll
    for (int i = 0; i < 16; ++i) {
        unsigned int v = w[threadIdx.x * 16 + i];
        unsigned int lo = v & 0xFFFFu;
        if (lo != 0u && (lo >> 8) <= 0x3Fu) ++c;
    }
    atomicAdd(&cnt, c);
    __syncthreads();
    if (threadIdx.x == 0) *flag = (cnt > 2560) ? 1 : 0;   // of 4096 samples
}

// ---------------------------------------------------------------------------
// NT GEMM, 64x64 tile, BK=64, 4 waves (each 32x32 via 2x2 of 16x16x32 bf16
// MFMA). A: dtype TA; B: always bf16 (ws intermediates); out: TOUT.
// Used for G1 (TRANS), G3 (TRANS), G5 (NORM).
template <int EPI, int PIPE, typename TA, typename TOUT>
__global__ __launch_bounds__(256)
void gemm_nt64(const int* __restrict__ flag,
               const TA* __restrict__ A, int lda,
               const hbf16* __restrict__ B, int ldb,
               TOUT* __restrict__ C0, TOUT* __restrict__ C1,
               hbf16* __restrict__ CWS, int ldc, int K)
{
    if ((*flag != 0) != (PIPE != 0)) return;   // uniform: dead pipeline exits

    __shared__ hbf16 As[64 * 64];
    __shared__ hbf16 Bs[64 * 64];

    const int tid  = threadIdx.x;
    const int lane = tid & 63;
    const int w    = tid >> 6;        // wave 0..3
    const int wm0  = (w >> 1) * 32;   // wave's 32x32 quadrant
    const int wn0  = (w & 1) * 32;

    const int m0 = blockIdx.y * 64;
    const int n0 = blockIdx.x * 64;

    const int srow = tid >> 3;            // 0..31
    const int scol = (tid & 7) * 8;       // element col

    const size_t a_base = (size_t)(m0 + srow) * lda + scol;
    const size_t b_base = (size_t)(n0 + srow) * ldb + scol;

    f32x4 acc[2][2];
#pragma unroll
    for (int i = 0; i < 2; ++i)
#pragma unroll
        for (int j = 0; j < 2; ++j)
            acc[i][j] = (f32x4){0.f, 0.f, 0.f, 0.f};

    const int mrow = lane & 15;          // fragment row within 16
    const int kq   = (lane >> 4) * 8;    // quad * 8 along K

    for (int k0 = 0; k0 < K; k0 += 64) {
        bf16x8 va0 = load8(A + a_base + k0);
        bf16x8 va1 = load8(A + a_base + (size_t)32 * lda + k0);
        bf16x8 vb0 = load8(B + b_base + k0);
        bf16x8 vb1 = load8(B + b_base + (size_t)32 * ldb + k0);

        __syncthreads();   // previous iter's ds_reads done before overwrite
        LDS8(As, srow,      scol) = va0;
        LDS8(As, srow + 32, scol) = va1;
        LDS8(Bs, srow,      scol) = vb0;
        LDS8(Bs, srow + 32, scol) = vb1;
        __syncthreads();   // staged

#pragma unroll
        for (int ks = 0; ks < 2; ++ks) {
            const int kc = ks * 32 + kq;
            bf16x8 a0 = LDS8C(As, wm0 + mrow,      kc);
            bf16x8 a1 = LDS8C(As, wm0 + 16 + mrow, kc);
            bf16x8 b0 = LDS8C(Bs, wn0 + mrow,      kc);
            bf16x8 b1 = LDS8C(Bs, wn0 + 16 + mrow, kc);
            acc[0][0] = __builtin_amdgcn_mfma_f32_16x16x32_bf16(a0, b0, acc[0][0], 0, 0, 0);
            acc[0][1] = __builtin_amdgcn_mfma_f32_16x16x32_bf16(a0, b1, acc[0][1], 0, 0, 0);
            acc[1][0] = __builtin_amdgcn_mfma_f32_16x16x32_bf16(a1, b0, acc[1][0], 0, 0, 0);
            acc[1][1] = __builtin_amdgcn_mfma_f32_16x16x32_bf16(a1, b1, acc[1][1], 0, 0, 0);
        }
    }

    // epilogue: C/D layout col=lane&15, row=(lane>>4)*4+reg  [m89/m91]
    const int cn = lane & 15;
    const int rq = (lane >> 4) * 4;
#pragma unroll
    for (int mt = 0; mt < 2; ++mt)
#pragma unroll
        for (int nt = 0; nt < 2; ++nt)
#pragma unroll
            for (int r = 0; r < 4; ++r) {
                int row = m0 + wm0 + mt * 16 + rq + r;
                int col = n0 + wn0 + nt * 16 + cn;
                float v = acc[mt][nt][r];
                if (EPI == EPI_RELU) v = v > 0.f ? v : 0.f;
                if (EPI == EPI_TRANS) {
                    store1(&C0[(size_t)col * ldc + row], v);
                } else if (EPI == EPI_SPLIT) {
                    if (col < D_Z) {
                        store1(&C0[(size_t)row * D_Z + col], v);
                        CWS[(size_t)row * D_Z + col] = __float2bfloat16(v);
                    } else {
                        store1(&C1[(size_t)row * D_Z + (col - D_Z)], v);
                    }
                } else {
                    store1(&C0[(size_t)row * ldc + col], v);
                }
            }
}

// ---------------------------------------------------------------------------
// Split-K x8, 64x128 tiles for the two adj GEMMs (K = 8192). NBLK = n-tiles
// of 128 (G2: 2, G4: 1 = full N, zero adj sharing). 1-D grid, lid
// decomposition n-fastest then m then k; bijective XCD swizzle keeps the two
// n-siblings (G2) on one XCD/L2. 4 waves in 2x2 grid, each 32x64 output:
// acc[2][4], 16 MFMA + 12 swizzled ds_read_b128 per 64-K step. f32 atomicAdd
// epilogue (device-scope, G12) into zeroed ws.
template <int PIPE, int NBLK, typename TA>
__global__ __launch_bounds__(256, 4)
void gemm_nt128_splitk(const int* __restrict__ flag,
                       const TA* __restrict__ A, int lda,
                       const hbf16* __restrict__ B, int ldb,
                       float* __restrict__ C, int ldc, int K)
{
    if ((*flag != 0) != (PIPE != 0)) return;

    __shared__ hbf16 As[64 * 64];     // 8 KB, swizzled
    __shared__ hbf16 Bs[128 * 64];    // 16 KB, swizzled

    // grid size divisible by 8 by construction
    const int q   = gridDim.x >> 3;
    const int lid = ((int)blockIdx.x & 7) * q + ((int)blockIdx.x >> 3);
    const int nb  = lid & (NBLK - 1);
    const int rem = lid / NBLK;
    const int mb  = rem & (N_NODES / 64 - 1);
    const int kb  = rem / (N_NODES / 64);

    const int tid  = threadIdx.x;
    const int lane = tid & 63;
    const int w    = tid >> 6;
    const int wm0  = (w >> 1) * 32;   // wave covers 32 (m) x 64 (n)
    const int wn0  = (w & 1) * 64;

    const int m0 = mb * 64;
    const int n0 = nb * 128;

    const int srow = tid >> 3;            // 0..31
    const int scol = (tid & 7) * 8;

    const size_t a_base = (size_t)(m0 + srow) * lda + scol;
    const size_t b_base = (size_t)(n0 + srow) * ldb + scol;

    f32x4 acc[2][4];
#pragma unroll
    for (int i = 0; i < 2; ++i)
#pragma unroll
        for (int j = 0; j < 4; ++j)
            acc[i][j] = (f32x4){0.f, 0.f, 0.f, 0.f};

    const int mrow = lane & 15;
    const int kq   = (lane >> 4) * 8;

    const int kchunk = K / KSPLIT;
    const int k_lo   = kb * kchunk;
    const int k_hi   = k_lo + kchunk;

    for (int k0 = k_lo; k0 < k_hi; k0 += 64) {
        bf16x8 va0 = load8(A + a_base + k0);
        bf16x8 va1 = load8(A + a_base + (size_t)32 * lda + k0);
        bf16x8 vb0 = load8(B + b_base + k0);
        bf16x8 vb1 = load8(B + b_base + (size_t)32 * ldb + k0);
        bf16x8 vb2 = load8(B + b_base + (size_t)64 * ldb + k0);
        bf16x8 vb3 = load8(B + b_base + (size_t)96 * ldb + k0);

        __syncthreads();
        LDS8(As, srow,      scol) = va0;
        LDS8(As, srow + 32, scol) = va1;
        LDS8(Bs, srow,      scol) = vb0;
        LDS8(Bs, srow + 32, scol) = vb1;
        LDS8(Bs, srow + 64, scol) = vb2;
        LDS8(Bs, srow + 96, scol) = vb3;
        __syncthreads();

#pragma unroll
        for (int ks = 0; ks < 2; ++ks) {
            const int kc = ks * 32 + kq;
            bf16x8 a0 = LDS8C(As, wm0 + mrow,      kc);
            bf16x8 a1 = LDS8C(As, wm0 + 16 + mrow, kc);
#pragma unroll
            for (int nt = 0; nt < 4; ++nt) {
                bf16x8 b = LDS8C(Bs, wn0 + nt * 16 + mrow, kc);
                acc[0][nt] = __builtin_amdgcn_mfma_f32_16x16x32_bf16(a0, b, acc[0][nt], 0, 0, 0);
                acc[1][nt] = __builtin_amdgcn_mfma_f32_16x16x32_bf16(a1, b, acc[1][nt], 0, 0, 0);
            }
        }
    }

    const int cn = lane & 15;
    const int rq = (lane >> 4) * 4;
#pragma unroll
    for (int mt = 0; mt < 2; ++mt)
#pragma unroll
        for (int nt = 0; nt < 4; ++nt)
#pragma unroll
            for (int r = 0; r < 4; ++r) {
                int row = m0 + wm0 + mt * 16 + rq + r;
                int col = n0 + wn0 + nt * 16 + cn;
                atomicAdd(&C[(size_t)row * ldc + col], acc[mt][nt][r]);
            }
}

// ---------------------------------------------------------------------------
// zero Hacc+Zc (contiguous, 3M floats) before split-K atomics
__global__ void zero_f32(float* __restrict__ p, int n4) {
    int i = blockIdx.x * 256 + threadIdx.x;
    if (i < n4) ((f32x4*)p)[i] = (f32x4){0.f, 0.f, 0.f, 0.f};
}

// H = relu(Hacc) -> bf16, 8192*256 elements, 4/thread
template <int PIPE>
__global__ void epi_relu(const int* __restrict__ flag,
                         const float* __restrict__ S, hbf16* __restrict__ H) {
    if ((*flag != 0) != (PIPE != 0)) return;
    int i = blockIdx.x * 256 + threadIdx.x;           // 524288 total
    f32x4 v = ((const f32x4*)S)[i];
    bf16x4 o;
#pragma unroll
    for (int j = 0; j < 4; ++j) {
        float f = v[j] > 0.f ? v[j] : 0.f;
        o[j] = (__bf16)f;
    }
    ((bf16x4*)H)[i] = o;
}

// Zc[8192,128] -> zmean TOUT[8192,64] (+ bf16 ws copy), zlog TOUT[8192,64]
template <int PIPE, typename T>
__global__ void epi_split(const int* __restrict__ flag,
                          const float* __restrict__ Zc,
                          T* __restrict__ zmean, T* __restrict__ zlog,
                          hbf16* __restrict__ zws) {
    if ((*flag != 0) != (PIPE != 0)) return;
    int i = blockIdx.x * 256 + threadIdx.x;           // 262144 total
    f32x4 v = ((const f32x4*)Zc)[i];
    int i4  = i << 2;
    int row = i4 >> 7;
    int col = i4 & 127;                               // multiple of 4, one half
    if (col < D_Z) {
        size_t o = (size_t)row * D_Z + col;
#pragma unroll
        for (int j = 0; j < 4; ++j) {
            store1(&zmean[o + j], v[j]);
            zws[o + j] = __float2bfloat16(v[j]);
        }
    } else {
        size_t o = (size_t)row * D_Z + (col - D_Z);
#pragma unroll
        for (int j = 0; j < 4; ++j) store1(&zlog[o + j], v[j]);
    }
}

// Wh[512,256] -> WhT[256,512] (bf16)
template <int PIPE, typename T>
__global__ void prep_whT(const int* __restrict__ flag,
                         const T* __restrict__ W, hbf16* __restrict__ WT) {
    if ((*flag != 0) != (PIPE != 0)) return;
    int o = blockIdx.x * 256 + threadIdx.x;   // 256*512 total
    int n = o >> 9;
    int k = o & 511;
    WT[o] = __float2bfloat16(tofloat(W[k * D_HID + n]));
}

// Wm[256,64], Wl[256,64] -> WcT[128,256] (bf16; rows 0..63 = Wm^T, 64..127 = Wl^T)
template <int PIPE, typename T>
__global__ void prep_wcT(const int* __restrict__ flag,
                         const T* __restrict__ Wm, const T* __restrict__ Wl,
                         hbf16* __restrict__ WcT) {
    if ((*flag != 0) != (PIPE != 0)) return;
    int o = blockIdx.x * 256 + threadIdx.x;   // 128*256 total
    int n = o >> 8;
    int k = o & 255;
    WcT[o] = __float2bfloat16(tofloat((n < D_Z) ? Wm[k * D_Z + n]
                                                : Wl[k * D_Z + (n - D_Z)]));
}

template <int PIPE, typename T>
static void launch_pipeline(void* const* d_in, void* d_out,
                            int* flag, hbf16* S1T, hbf16* H, hbf16* WhT,
                            hbf16* WcT, hbf16* TT, hbf16* ZmWS,
                            float* Hacc, float* Zc,
                            hipStream_t stream) {
    const T* x   = (const T*)d_in[0];
    const T* adj = (const T*)d_in[1];
    const T* Wh  = (const T*)d_in[2];
    const T* Wm  = (const T*)d_in[3];
    const T* Wl  = (const T*)d_in[4];

    T* recon = (T*)d_out;                              // [8192,8192]
    T* zmean = recon + (size_t)N_NODES * N_NODES;      // [8192,64]
    T* zlog  = zmean + (size_t)N_NODES * D_Z;          // [8192,64]

    prep_whT<PIPE, T><<<512, 256, 0, stream>>>(flag, Wh, WhT);
    prep_wcT<PIPE, T><<<128, 256, 0, stream>>>(flag, Wm, Wl, WcT);

    // G1: S1T = (x @ Wh)^T        M=8192 N=256 K=512
    gemm_nt64<EPI_TRANS, PIPE, T, hbf16>
        <<<dim3(D_HID / 64, N_NODES / 64), 256, 0, stream>>>(
        flag, x, D_INF, WhT, D_INF, S1T, (hbf16*)nullptr, (hbf16*)nullptr,
        N_NODES, D_INF);

    // G2: Hacc += adj @ S1 (split-K x8, NBLK=2)   M=8192 N=256 K=8192
    gemm_nt128_splitk<PIPE, 2, T>
        <<<2 * (N_NODES / 64) * KSPLIT, 256, 0, stream>>>(
        flag, adj, N_NODES, S1T, N_NODES, Hacc, D_HID, N_NODES);
    epi_relu<PIPE><<<2048, 256, 0, stream>>>(flag, Hacc, H);

    // G3: TT = (H @ [Wm|Wl])^T    M=8192 N=128 K=256
    gemm_nt64<EPI_TRANS, PIPE, hbf16, hbf16>
        <<<dim3(2 * D_Z / 64, N_NODES / 64), 256, 0, stream>>>(
        flag, H, D_HID, WcT, D_HID, TT, (hbf16*)nullptr, (hbf16*)nullptr,
        N_NODES, D_HID);

    // G4: Zc += adj @ T (split-K x8, NBLK=1 = full N, adj fetch 1x)
    gemm_nt128_splitk<PIPE, 1, T>
        <<<1 * (N_NODES / 64) * KSPLIT, 256, 0, stream>>>(
        flag, adj, N_NODES, TT, N_NODES, Zc, 2 * D_Z, N_NODES);
    epi_split<PIPE, T><<<1024, 256, 0, stream>>>(flag, Zc, zmean, zlog, ZmWS);

    // G5: recon = Zm @ Zm^T       M=8192 N=8192 K=64
    gemm_nt64<EPI_NORM, PIPE, hbf16, T>
        <<<dim3(N_NODES / 64, N_NODES / 64), 256, 0, stream>>>(
        flag, ZmWS, D_Z, ZmWS, D_Z, recon, (T*)nullptr, (hbf16*)nullptr,
        N_NODES, D_Z);
}

extern "C" void kernel_launch(void* const* d_in, const int* in_sizes, int n_in,
                              void* d_out, int out_size, void* d_ws, size_t ws_size,
                              hipStream_t stream) {
    int*   flag = (int*)d_ws;
    hbf16* S1T  = (hbf16*)((char*)d_ws + 256);                  // [256,8192]  4 MB
    hbf16* H    = S1T + (size_t)D_HID * N_NODES;                // [8192,256]  4 MB
    hbf16* WhT  = H   + (size_t)N_NODES * D_HID;                // [256,512]
    hbf16* WcT  = WhT + (size_t)D_HID * D_INF;                  // [128,256]
    hbf16* TT   = WcT + (size_t)2 * D_Z * D_HID;                // [128,8192]  2 MB
    hbf16* ZmWS = TT  + (size_t)2 * D_Z * N_NODES;              // [8192,64]   1 MB
    float* Hacc = (float*)(ZmWS + (size_t)N_NODES * D_Z);       // [8192,256]  8 MB f32
    float* Zc   = Hacc + (size_t)N_NODES * D_HID;               // [8192,128]  4 MB f32

    detect_dtype<<<1, 256, 0, stream>>>((const unsigned int*)d_in[1], flag);

    // zero split-K accumulators (Hacc|Zc contiguous: 3M floats)
    zero_f32<<<3072, 256, 0, stream>>>(
        Hacc, (N_NODES * D_HID + N_NODES * 2 * D_Z) / 4);

    launch_pipeline<1, hbf16>(d_in, d_out, flag, S1T, H, WhT, WcT, TT, ZmWS,
                              Hacc, Zc, stream);
    launch_pipeline<0, float>(d_in, d_out, flag, S1T, H, WhT, WcT, TT, ZmWS,
                              Hacc, Zc, stream);
}